// Round 13
// baseline (63.018 us; speedup 1.0000x reference)
//
#include <hip/hip_runtime.h>

typedef float v2f __attribute__((ext_vector_type(2)));

#define IMG 512
#define OUT_N 502
#define NPLANE 48
#define NSTRIP 32            // 16 output rows per strip
#define SROWS 16
#define RPITCH 133           // region pitch (float4 units) in row buffer
#define ROWP (4*RPITCH)      // 532 float4 per buffered V-row
#define C1c 0.0001f
#define C2c 0.0004f

// ssim from H-blurred (Bs, Bd, BP, BM) where s=x+y, d=x-y:
// mux=(Bs+Bd)/2, muy=(Bs-Bd)/2; BP=blur(s^2), BM=blur(d^2).
// v_rcp_f32: den >= C1*C2 > 0; ~1e-6 rel err, far under tolerance.
__device__ __forceinline__ float ssim_px(float Bs, float Bd, float BP, float BM) {
    float mx = 0.5f*(Bs + Bd), my = 0.5f*(Bs - Bd);
    float A = mx*mx, B = my*my, mxy = mx*my;
    float sumsq = 0.5f*(BP + BM) - A - B;   // sigx2 + sigy2
    float sxy   = 0.25f*(BP - BM) - mxy;    // sigxy
    float num = (2.f*mxy + C1c) * (2.f*sxy + C2c);
    float den = (A + B + C1c) * (sumsq + C2c);
    return num * __builtin_amdgcn_rcpf(den);
}

// 512 threads, 1 col/thread in V, 4 cols/thread in H. 4-row groups,
// DOUBLE-buffered (buf[2], 68 KB): segment = {GISSUE; HPASS(T-1); VWR(T);
// GINSERT; barrier} -> 4 barriers/strip (was 8), and each group's global
// loads get ~HPASS+VWR of slack before consumption. Prologue issues ALL 18
// rows before any ring-insert (kills the serial depth-2 fill, ~6300->~1000cy).
// Raw s_barrier + lgkmcnt(0) only: prefetched loads never drained at barriers.
__global__ __launch_bounds__(512, 2) void ssim_strip(
    const float* __restrict__ in, const float* __restrict__ tgt,
    const float* __restrict__ w, float* __restrict__ partial)
{
    __shared__ float4 buf[2][4*ROWP];   // 2 x 34 KB
    __shared__ float g1s[16];
    __shared__ float red[8];

    const int tid   = threadIdx.x;
    const int strip = blockIdx.x;
    const int plane = blockIdx.y;
    const int r0 = strip * SROWS;
    const float* __restrict__ ip = in  + (size_t)plane * (IMG*IMG);
    const float* __restrict__ tp = tgt + (size_t)plane * (IMG*IMG);

    // 1D factor = row sums of 2D kernel (exact: w2d = outer(g,g), sum g = 1)
    if (tid < 11) {
        float s = 0.f;
        #pragma unroll
        for (int j = 0; j < 11; ++j) s += w[tid*11 + j];
        g1s[tid] = s;
    }
    __syncthreads();
    float g[11];
    #pragma unroll
    for (int j = 0; j < 11; ++j)
        g[j] = __int_as_float(__builtin_amdgcn_readfirstlane(__float_as_int(g1s[j])));

    v2f sd[16];                 // ring: input row k -> slot k & 15 (static)
    float acc = 0.f;
    const int wbase = (tid & 3) * RPITCH + (tid >> 2);   // V-write addr (f4)
    const int hr = tid >> 7;    // H: row in group (0..3), wave-uniform
    const int ht = tid & 127;   // H: col group -> cols 4ht..4ht+3
    const int hb = hr * ROWP + ht;

#define INS(ROW, X, Y) sd[(ROW) & 15] = (v2f){(X) + (Y), (X) - (Y)};

    // V-blur rows 4T..4T+3 (input row 4T+j feeds out-row v for v<=j<=v+10,
    // weight g[j-v]); squares shared by all 4 rows. Writes buf[T&1].
#define VWR(T) \
    { v2f a0=(v2f)(0.f),p0=(v2f)(0.f),a1=(v2f)(0.f),p1=(v2f)(0.f); \
      v2f a2=(v2f)(0.f),p2=(v2f)(0.f),a3=(v2f)(0.f),p3=(v2f)(0.f); \
      _Pragma("unroll") \
      for (int j = 0; j < 14; ++j) { \
        v2f s = sd[(4*(T) + j) & 15]; \
        v2f q = s * s; \
        if (j <= 10)           { const float wj=g[j];   a0+=wj*s; p0+=wj*q; } \
        if (j >= 1 && j <= 11) { const float wj=g[j-1]; a1+=wj*s; p1+=wj*q; } \
        if (j >= 2 && j <= 12) { const float wj=g[j-2]; a2+=wj*s; p2+=wj*q; } \
        if (j >= 3)            { const float wj=g[j-3]; a3+=wj*s; p3+=wj*q; } \
      } \
      buf[(T)&1][0*ROWP + wbase] = make_float4(a0.x, a0.y, p0.x, p0.y); \
      buf[(T)&1][1*ROWP + wbase] = make_float4(a1.x, a1.y, p1.x, p1.y); \
      buf[(T)&1][2*ROWP + wbase] = make_float4(a2.x, a2.y, p2.x, p2.y); \
      buf[(T)&1][3*ROWP + wbase] = make_float4(a3.x, a3.y, p3.x, p3.y); }

    // H-pass group T from buf[T&1]: tap col 4ht+j at region j&3, idx ht+(j>>2).
#define HPASS(T) \
    { v2f s0=(v2f)(0.f),q0=(v2f)(0.f),s1=(v2f)(0.f),q1=(v2f)(0.f); \
      v2f s2=(v2f)(0.f),q2=(v2f)(0.f),s3=(v2f)(0.f),q3=(v2f)(0.f); \
      _Pragma("unroll") \
      for (int j = 0; j < 14; ++j) { \
        float4 v = buf[(T)&1][hb + (j&3)*RPITCH + (j>>2)]; \
        v2f vs = (v2f){v.x, v.y}, vp = (v2f){v.z, v.w}; \
        if (j <= 10)           { const float wj=g[j];   s0+=wj*vs; q0+=wj*vp; } \
        if (j >= 1 && j <= 11) { const float wj=g[j-1]; s1+=wj*vs; q1+=wj*vp; } \
        if (j >= 2 && j <= 12) { const float wj=g[j-2]; s2+=wj*vs; q2+=wj*vp; } \
        if (j >= 3)            { const float wj=g[j-3]; s3+=wj*vs; q3+=wj*vp; } \
      } \
      const int oy = r0 + 4*(T) + hr; \
      const int oc = 4*ht; \
      if (oy < OUT_N) { \
        if (oc     < OUT_N) acc += ssim_px(s0.x,s0.y,q0.x,q0.y); \
        if (oc + 1 < OUT_N) acc += ssim_px(s1.x,s1.y,q1.x,q1.y); \
        if (oc + 2 < OUT_N) acc += ssim_px(s2.x,s2.y,q2.x,q2.y); \
        if (oc + 3 < OUT_N) acc += ssim_px(s3.x,s3.y,q3.x,q3.y); \
      } }

#define BARRIER() \
    asm volatile("s_waitcnt lgkmcnt(0)" ::: "memory"); \
    __builtin_amdgcn_s_barrier(); \
    __builtin_amdgcn_sched_barrier(0);

    // issue 4 rows BASE..BASE+3 into fx/fy (static idx, stays in regs)
#define GLOAD(BASE) \
    _Pragma("unroll") \
    for (int q = 0; q < 4; ++q) { \
        const int rr = r0 + (BASE) + q; \
        fx[q] = (rr < IMG) ? ip[rr*IMG + tid] : 0.f; \
        fy[q] = (rr < IMG) ? tp[rr*IMG + tid] : 0.f; \
    }
#define GINS(BASE) \
    INS((BASE)+0, fx[0], fy[0]) INS((BASE)+1, fx[1], fy[1]) \
    INS((BASE)+2, fx[2], fy[2]) INS((BASE)+3, fx[3], fy[3])

    // ---- Prologue: issue ALL loads for rows 0..17 before any consume ----
    float px[18], py[18];
    #pragma unroll
    for (int r = 0; r < 18; ++r) {
        const int rr = r0 + r;
        px[r] = (rr < IMG) ? ip[rr*IMG + tid] : 0.f;
        py[r] = (rr < IMG) ? tp[rr*IMG + tid] : 0.f;
    }
    #pragma unroll
    for (int r = 0; r < 14; ++r) { INS(r, px[r], py[r]) }

    float fx[4], fy[4];

    // ---- S0: V(0)->bufA; insert rows 14-17 (already loaded, huge slack) ----
    VWR(0)
    INS(14, px[14], py[14]) INS(15, px[15], py[15])
    INS(16, px[16], py[16]) INS(17, px[17], py[17])
    BARRIER()
    // ---- S1: issue 18-21; H(0) from bufA; V(1)->bufB; insert 18-21 ----
    GLOAD(18)
    HPASS(0)
    VWR(1)
    GINS(18)
    BARRIER()
    // ---- S2: issue 22-25; H(1) from bufB; V(2)->bufA; insert 22-25 ----
    GLOAD(22)
    HPASS(1)
    VWR(2)
    GINS(22)
    BARRIER()
    // ---- S3: H(2) from bufA; V(3)->bufB ----
    HPASS(2)
    VWR(3)
    BARRIER()
    // ---- tail ----
    HPASS(3)

    // block reduction: wave shuffle, then 8 wave-partials through LDS
    #pragma unroll
    for (int off = 32; off > 0; off >>= 1)
        acc += __shfl_down(acc, off, 64);
    const int lane = tid & 63, wv = tid >> 6;
    if (lane == 0) red[wv] = acc;
    __syncthreads();
    if (tid == 0) {
        float t = 0.f;
        #pragma unroll
        for (int i = 0; i < 8; ++i) t += red[i];
        partial[plane * NSTRIP + strip] = t;
    }
}

// Deterministic final reduction: fixed traversal, double accumulation.
__global__ __launch_bounds__(256) void ssim_final(
    const float* __restrict__ partial, int n, float* __restrict__ out)
{
    __shared__ double red[256];
    double s = 0.0;
    for (int i = threadIdx.x; i < n; i += 256) s += (double)partial[i];
    red[threadIdx.x] = s;
    __syncthreads();
    for (int off = 128; off > 0; off >>= 1) {
        if (threadIdx.x < off) red[threadIdx.x] += red[threadIdx.x + off];
        __syncthreads();
    }
    if (threadIdx.x == 0) out[0] = (float)(1.0 - red[0] / (double)NPLANE);
}

extern "C" void kernel_launch(void* const* d_in, const int* in_sizes, int n_in,
                              void* d_out, int out_size, void* d_ws, size_t ws_size,
                              hipStream_t stream) {
    const float* in  = (const float*)d_in[0];
    const float* tgt = (const float*)d_in[1];
    const float* wt  = (const float*)d_in[2];
    float* out  = (float*)d_out;
    float* part = (float*)d_ws;

    dim3 grid(NSTRIP, NPLANE);   // 32 strips x 48 planes = 1536 blocks
    ssim_strip<<<grid, 512, 0, stream>>>(in, tgt, wt, part);
    ssim_final<<<1, 256, 0, stream>>>(part, NSTRIP * NPLANE, out);
}

// Round 14
// 53.281 us; speedup vs baseline: 1.1827x; 1.1827x over previous
//
#include <hip/hip_runtime.h>

typedef float v2f __attribute__((ext_vector_type(2)));

#define IMG 512
#define OUT_N 502
#define NPLANE 48
#define NSTRIP 32            // 16 output rows per strip
#define SROWS 16
#define RPITCH 133           // region pitch (float4 units) in row buffer
#define ROWP (4*RPITCH)      // 532 float4 per buffered V-row
#define C1c 0.0001f
#define C2c 0.0004f

// ssim from H-blurred (Bs, Bd, BP, BM) where s=x+y, d=x-y:
// mux=(Bs+Bd)/2, muy=(Bs-Bd)/2; BP=blur(s^2), BM=blur(d^2).
// v_rcp_f32: den >= C1*C2 > 0; ~1e-6 rel err, far under tolerance.
__device__ __forceinline__ float ssim_px(float Bs, float Bd, float BP, float BM) {
    float mx = 0.5f*(Bs + Bd), my = 0.5f*(Bs - Bd);
    float A = mx*mx, B = my*my, mxy = mx*my;
    float sumsq = 0.5f*(BP + BM) - A - B;   // sigx2 + sigy2
    float sxy   = 0.25f*(BP - BM) - mxy;    // sigxy
    float num = (2.f*mxy + C1c) * (2.f*sxy + C2c);
    float den = (A + B + C1c) * (sumsq + C2c);
    return num * __builtin_amdgcn_rcpf(den);
}

// 512 threads, 1 col/thread in V, 4 cols/thread in H, 4-row barrier groups,
// single 34KB buffer (4 blocks/CU by LDS). INTERIOR template (strips 0..30):
// no row clamps on loads, no oy predicates -- only strip 31 pays edge code.
// Batch-18 prologue + depth-2 group prefetch: every global load has >= 1 full
// segment (~1400cy) before its ring-insert. Raw s_barrier + lgkmcnt(0) only.
template<bool INTERIOR>
__global__ __launch_bounds__(512, 4) void ssim_strip(
    const float* __restrict__ in, const float* __restrict__ tgt,
    const float* __restrict__ w, float* __restrict__ partial, int strip_base)
{
    __shared__ float4 buf[4*ROWP];      // 34 KB
    __shared__ float g1s[16];
    __shared__ float red[8];

    const int tid   = threadIdx.x;
    const int strip = blockIdx.x + strip_base;
    const int plane = blockIdx.y;
    const int r0 = strip * SROWS;
    const float* __restrict__ ip = in  + (size_t)plane * (IMG*IMG);
    const float* __restrict__ tp = tgt + (size_t)plane * (IMG*IMG);

    // 1D factor = row sums of 2D kernel (exact: w2d = outer(g,g), sum g = 1)
    if (tid < 11) {
        float s = 0.f;
        #pragma unroll
        for (int j = 0; j < 11; ++j) s += w[tid*11 + j];
        g1s[tid] = s;
    }
    __syncthreads();
    float g[11];
    #pragma unroll
    for (int j = 0; j < 11; ++j)
        g[j] = __int_as_float(__builtin_amdgcn_readfirstlane(__float_as_int(g1s[j])));

    v2f sd[16];                 // ring: input row k -> slot k & 15 (static)
    float acc = 0.f;
    const int wbase = (tid & 3) * RPITCH + (tid >> 2);   // V-write addr (f4)
    const int hr = tid >> 7;    // H: row in group (0..3), wave-uniform
    const int ht = tid & 127;   // H: col group -> cols 4ht..4ht+3
    const int hb = hr * ROWP + ht;

#define INS(ROW, X, Y) sd[(ROW) & 15] = (v2f){(X) + (Y), (X) - (Y)};

    // V-blur rows 4T..4T+3 (input row 4T+j feeds out-row v for v<=j<=v+10,
    // weight g[j-v]); squares shared by all 4 rows.
#define VWR(T) \
    { v2f a0=(v2f)(0.f),p0=(v2f)(0.f),a1=(v2f)(0.f),p1=(v2f)(0.f); \
      v2f a2=(v2f)(0.f),p2=(v2f)(0.f),a3=(v2f)(0.f),p3=(v2f)(0.f); \
      _Pragma("unroll") \
      for (int j = 0; j < 14; ++j) { \
        v2f s = sd[(4*(T) + j) & 15]; \
        v2f q = s * s; \
        if (j <= 10)           { const float wj=g[j];   a0+=wj*s; p0+=wj*q; } \
        if (j >= 1 && j <= 11) { const float wj=g[j-1]; a1+=wj*s; p1+=wj*q; } \
        if (j >= 2 && j <= 12) { const float wj=g[j-2]; a2+=wj*s; p2+=wj*q; } \
        if (j >= 3)            { const float wj=g[j-3]; a3+=wj*s; p3+=wj*q; } \
      } \
      buf[0*ROWP + wbase] = make_float4(a0.x, a0.y, p0.x, p0.y); \
      buf[1*ROWP + wbase] = make_float4(a1.x, a1.y, p1.x, p1.y); \
      buf[2*ROWP + wbase] = make_float4(a2.x, a2.y, p2.x, p2.y); \
      buf[3*ROWP + wbase] = make_float4(a3.x, a3.y, p3.x, p3.y); }

    // H-pass: tap col 4ht+j lives at region j&3, idx ht+(j>>2).
#define HPASS(T) \
    { v2f s0=(v2f)(0.f),q0=(v2f)(0.f),s1=(v2f)(0.f),q1=(v2f)(0.f); \
      v2f s2=(v2f)(0.f),q2=(v2f)(0.f),s3=(v2f)(0.f),q3=(v2f)(0.f); \
      _Pragma("unroll") \
      for (int j = 0; j < 14; ++j) { \
        float4 v = buf[hb + (j&3)*RPITCH + (j>>2)]; \
        v2f vs = (v2f){v.x, v.y}, vp = (v2f){v.z, v.w}; \
        if (j <= 10)           { const float wj=g[j];   s0+=wj*vs; q0+=wj*vp; } \
        if (j >= 1 && j <= 11) { const float wj=g[j-1]; s1+=wj*vs; q1+=wj*vp; } \
        if (j >= 2 && j <= 12) { const float wj=g[j-2]; s2+=wj*vs; q2+=wj*vp; } \
        if (j >= 3)            { const float wj=g[j-3]; s3+=wj*vs; q3+=wj*vp; } \
      } \
      const int oc = 4*ht; \
      bool rowok = true; \
      if (!INTERIOR) rowok = (r0 + 4*(T) + hr) < OUT_N; \
      if (rowok) { \
        if (oc     < OUT_N) acc += ssim_px(s0.x,s0.y,q0.x,q0.y); \
        if (oc + 1 < OUT_N) acc += ssim_px(s1.x,s1.y,q1.x,q1.y); \
        if (oc + 2 < OUT_N) acc += ssim_px(s2.x,s2.y,q2.x,q2.y); \
        if (oc + 3 < OUT_N) acc += ssim_px(s3.x,s3.y,q3.x,q3.y); \
      } }

#define BARRIER() \
    asm volatile("s_waitcnt lgkmcnt(0)" ::: "memory"); \
    __builtin_amdgcn_s_barrier(); \
    __builtin_amdgcn_sched_barrier(0);

    // load 1 row (clamped only in the edge kernel)
#define LD1(ROW, X, Y) \
    { const int rr = r0 + (ROW); \
      if (INTERIOR) { X = ip[rr*IMG + tid]; Y = tp[rr*IMG + tid]; } \
      else { X = (rr < IMG) ? ip[rr*IMG + tid] : 0.f; \
             Y = (rr < IMG) ? tp[rr*IMG + tid] : 0.f; } }

    // ---- Prologue: batch-issue rows 0..17, insert 0..13, hold 14..17 ----
    float px[18], py[18];
    #pragma unroll
    for (int r = 0; r < 18; ++r) { LD1(r, px[r], py[r]) }
    #pragma unroll
    for (int r = 0; r < 14; ++r) { INS(r, px[r], py[r]) }

    float aX[4], aY[4], bX[4], bY[4];
    #pragma unroll
    for (int q = 0; q < 4; ++q) { LD1(18 + q, aX[q], aY[q]) }   // set A: rows 18-21

    // ---- Seg 0 ----
    VWR(0)
    INS(14, px[14], py[14]) INS(15, px[15], py[15])
    INS(16, px[16], py[16]) INS(17, px[17], py[17])
    BARRIER()
    #pragma unroll
    for (int q = 0; q < 4; ++q) { LD1(22 + q, bX[q], bY[q]) }   // set B: rows 22-25
    HPASS(0)
    INS(18, aX[0], aY[0]) INS(19, aX[1], aY[1])
    INS(20, aX[2], aY[2]) INS(21, aX[3], aY[3])
    BARRIER()
    // ---- Seg 1 ----
    VWR(1)
    BARRIER()
    HPASS(1)
    INS(22, bX[0], bY[0]) INS(23, bX[1], bY[1])
    INS(24, bX[2], bY[2]) INS(25, bX[3], bY[3])
    BARRIER()
    // ---- Seg 2 ----
    VWR(2)
    BARRIER()
    HPASS(2)
    BARRIER()
    // ---- Seg 3 ----
    VWR(3)
    BARRIER()
    HPASS(3)

    // block reduction: wave shuffle, then 8 wave-partials through LDS
    #pragma unroll
    for (int off = 32; off > 0; off >>= 1)
        acc += __shfl_down(acc, off, 64);
    const int lane = tid & 63, wv = tid >> 6;
    if (lane == 0) red[wv] = acc;
    __syncthreads();
    if (tid == 0) {
        float t = 0.f;
        #pragma unroll
        for (int i = 0; i < 8; ++i) t += red[i];
        partial[plane * NSTRIP + strip] = t;
    }
}

// Deterministic final reduction: fixed traversal, double accumulation.
__global__ __launch_bounds__(256) void ssim_final(
    const float* __restrict__ partial, int n, float* __restrict__ out)
{
    __shared__ double red[256];
    double s = 0.0;
    for (int i = threadIdx.x; i < n; i += 256) s += (double)partial[i];
    red[threadIdx.x] = s;
    __syncthreads();
    for (int off = 128; off > 0; off >>= 1) {
        if (threadIdx.x < off) red[threadIdx.x] += red[threadIdx.x + off];
        __syncthreads();
    }
    if (threadIdx.x == 0) out[0] = (float)(1.0 - red[0] / (double)NPLANE);
}

extern "C" void kernel_launch(void* const* d_in, const int* in_sizes, int n_in,
                              void* d_out, int out_size, void* d_ws, size_t ws_size,
                              hipStream_t stream) {
    const float* in  = (const float*)d_in[0];
    const float* tgt = (const float*)d_in[1];
    const float* wt  = (const float*)d_in[2];
    float* out  = (float*)d_out;
    float* part = (float*)d_ws;

    dim3 gridI(NSTRIP - 1, NPLANE);   // strips 0..30: fully interior rows
    ssim_strip<true><<<gridI, 512, 0, stream>>>(in, tgt, wt, part, 0);
    dim3 gridE(1, NPLANE);            // strip 31: row-edge handling
    ssim_strip<false><<<gridE, 512, 0, stream>>>(in, tgt, wt, part, NSTRIP - 1);
    ssim_final<<<1, 256, 0, stream>>>(part, NSTRIP * NPLANE, out);
}